// Round 11
// baseline (101.122 us; speedup 1.0000x reference)
//
#include <hip/hip_runtime.h>

#define SB 8
#define SS 2048
#define SD 1024
#define SH 64

typedef float f32x4 __attribute__((ext_vector_type(4)));
typedef __bf16 bf16x8 __attribute__((ext_vector_type(8)));

__device__ __forceinline__ unsigned short f2bf(float f) {
  union { float f; unsigned int u; } v; v.f = f;
  unsigned int u = v.u;
  unsigned int r = u + 0x7FFFu + ((u >> 16) & 1u);
  return (unsigned short)(r >> 16);
}

__device__ __forceinline__ bf16x8 asbf(f32x4 x) {
  union { f32x4 f; bf16x8 b; } u; u.f = x; return u.b;
}

// Wt[hc][d] = W_{hc/64}[d][hc&63] as bf16, hc in [0,192), d in [0,1024)
__global__ void prep_wt(const float* __restrict__ Wq, const float* __restrict__ Wk,
                        const float* __restrict__ Wv, unsigned short* __restrict__ Wt) {
  int idx = blockIdx.x * 256 + threadIdx.x;
  int hc = idx >> 10, d = idx & 1023;
  const float* W = (hc < 64) ? Wq : (hc < 128) ? Wk : Wv;
  int h = hc & 63;
  Wt[idx] = f2bf(W[d * SH + h]);
}

// QKV projection v3 (r10, kept): B-tile DMA-staged dbuf LDS, pre-swizzled source.
__global__ void __launch_bounds__(512, 2) proj(
    const float* __restrict__ x, const unsigned short* __restrict__ Wt,
    unsigned short* __restrict__ Q, unsigned short* __restrict__ K,
    unsigned short* __restrict__ Vt) {
  __shared__ unsigned short xs[64 * 64];        // 8 KB A tile, cg ^= (row&7)
  __shared__ unsigned short Bl[2][192 * 64];    // 2 x 24 KB B tiles

  int tid = threadIdx.x;
  int w = tid >> 6, lane = tid & 63;
  int l15 = lane & 15, kg = lane >> 4;
  int wr = w >> 2, wc = w & 3;
  int m0 = blockIdx.x * 64;

  int srow = tid >> 3, sseg = tid & 7;
  const float* xp = x + (size_t)(m0 + srow) * SD + sseg * 8;
  unsigned short* swp = xs + srow * 64 + ((sseg ^ (srow & 7)) * 8);

#define STAGEB(tt, buf)                                                          \
  {                                                                              \
    _Pragma("unroll") for (int j = 0; j < 3; ++j) {                              \
      int Lb = w * 1024 + j * 8192 + lane * 16;                                  \
      int c = Lb >> 7, cb = Lb & 127;                                            \
      const char* srcp = (const char*)Wt + (size_t)c * 2048 + (tt) * 128 +       \
                         (cb ^ ((c & 7) << 4));                                  \
      __builtin_amdgcn_global_load_lds(                                          \
          (const __attribute__((address_space(1))) unsigned int*)(const void*)srcp, \
          (__attribute__((address_space(3))) unsigned int*)(void*)                \
              ((char*)&Bl[(buf)][0] + w * 1024 + j * 8192),                      \
          16, 0, 0);                                                             \
    }                                                                            \
  }

  float4 ra = *(const float4*)xp;
  float4 rb = *(const float4*)(xp + 4);

  f32x4 acc[2][3];
#pragma unroll
  for (int mt = 0; mt < 2; ++mt)
#pragma unroll
    for (int nt = 0; nt < 3; ++nt) acc[mt][nt] = f32x4{0.f, 0.f, 0.f, 0.f};

  STAGEB(0, 0);

  for (int t = 0; t < 16; ++t) {
    union { unsigned short us[8]; bf16x8 v; } cv;
    cv.us[0] = f2bf(ra.x); cv.us[1] = f2bf(ra.y);
    cv.us[2] = f2bf(ra.z); cv.us[3] = f2bf(ra.w);
    cv.us[4] = f2bf(rb.x); cv.us[5] = f2bf(rb.y);
    cv.us[6] = f2bf(rb.z); cv.us[7] = f2bf(rb.w);
    *(bf16x8*)swp = cv.v;
    __syncthreads();

    if (t < 15) {
      STAGEB(t + 1, (t + 1) & 1);
      ra = *(const float4*)(xp + (t + 1) * 64);
      rb = *(const float4*)(xp + (t + 1) * 64 + 4);
    }

    const char* Bb = (const char*)&Bl[t & 1][0];
#pragma unroll
    for (int ks = 0; ks < 2; ++ks) {
      bf16x8 af[2];
#pragma unroll
      for (int mt = 0; mt < 2; ++mt) {
        int row = wr * 32 + mt * 16 + l15;
        int cg = ks * 4 + kg;
        af[mt] = *(const bf16x8*)(xs + row * 64 + ((cg ^ (row & 7)) * 8));
      }
#pragma unroll
      for (int nt = 0; nt < 3; ++nt) {
        int c = wc * 48 + nt * 16 + l15;
        int kb = (ks * 32 + kg * 8) * 2;
        bf16x8 bfr = *(const bf16x8*)(Bb + c * 128 + (kb ^ ((c & 7) << 4)));
#pragma unroll
        for (int mt = 0; mt < 2; ++mt)
          acc[mt][nt] = __builtin_amdgcn_mfma_f32_16x16x32_bf16(af[mt], bfr, acc[mt][nt], 0, 0, 0);
      }
    }
    __syncthreads();
  }

#pragma unroll
  for (int nt = 0; nt < 3; ++nt) {
    int c = wc * 48 + nt * 16 + l15;
    int mat = c >> 6, h = c & 63;
#pragma unroll
    for (int mt = 0; mt < 2; ++mt)
#pragma unroll
      for (int r = 0; r < 4; ++r) {
        int row = m0 + wr * 32 + mt * 16 + kg * 4 + r;
        unsigned short bv = f2bf(acc[mt][nt][r]);
        if (mat == 0) {
          Q[(size_t)row * SH + h] = bv;
        } else if (mat == 1) {
          K[(size_t)row * SH + h] = bv;
        } else {
          int bb = row >> 11, key = row & 2047;
          Vt[((size_t)bb * SH + h) * SS + key] = bv;
        }
      }
  }
}

// Attention: r10 structure + QK phase rebuilt as an asm-pipelined load loop
// (AITER pattern): volatile global_load_dwordx4 (can't be sunk by hipcc) in a
// 2-slot register ring, counted s_waitcnt vmcnt(4) + sched_barrier(0) before
// each 4-MFMA group. (512,2) for pipeline VGPRs; 2 blocks/CU (attn measured
// insensitive 2 vs 4 blocks/CU in r4/r5).
__global__ void __launch_bounds__(512, 2) attn(
    const unsigned short* __restrict__ Q, const unsigned short* __restrict__ Kb,
    const unsigned short* __restrict__ Vt, float* __restrict__ out,
    float* __restrict__ wts) {
  __shared__ float pf[8][16][68];
  __shared__ float mS[8][16], sgS[8][16];

  int b = blockIdx.x & 7, rg = blockIdx.x >> 3;
  int w = threadIdx.x >> 6, lane = threadIdx.x & 63;
  int l15 = lane & 15, kg = lane >> 4;
  int q0 = rg * 16;
  int kv0 = w * 256;

  const unsigned short* Qb  = Q  + (size_t)b * SS * SH;
  const unsigned short* Kbb = Kb + (size_t)b * SS * SH;
  const unsigned short* Vtb = Vt + (size_t)b * SH * SS;

  // qf also via asm so the compiler's waitcnt pass tracks no pending vmem
  // of its own inside the pipelined region.
  f32x4 qr0, qr1;
  {
    const unsigned short* qp0 = Qb + (size_t)(q0 + l15) * SH + kg * 8;
    const unsigned short* qp1 = qp0 + 32;
    asm volatile("global_load_dwordx4 %0, %1, off" : "=v"(qr0) : "v"(qp0));
    asm volatile("global_load_dwordx4 %0, %1, off" : "=v"(qr1) : "v"(qp1));
  }

  f32x4 s[4][4];
#pragma unroll
  for (int kt = 0; kt < 4; ++kt)
#pragma unroll
    for (int n = 0; n < 4; ++n) s[kt][n] = f32x4{0.f, 0.f, 0.f, 0.f};

  f32x4 kA0, kA1, kA2, kA3, kB0, kB1, kB2, kB3;

#define KADDR(KT, KS, N) \
  (Kbb + (size_t)(kv0 + (KT) * 64 + (N) * 16 + l15) * SH + (KS) * 32 + kg * 8)
#define KISSUE(S0, S1, S2, S3, KT, KS)                                            \
  asm volatile("global_load_dwordx4 %0, %1, off" : "=v"(S0) : "v"(KADDR(KT, KS, 0))); \
  asm volatile("global_load_dwordx4 %0, %1, off" : "=v"(S1) : "v"(KADDR(KT, KS, 1))); \
  asm volatile("global_load_dwordx4 %0, %1, off" : "=v"(S2) : "v"(KADDR(KT, KS, 2))); \
  asm volatile("global_load_dwordx4 %0, %1, off" : "=v"(S3) : "v"(KADDR(KT, KS, 3)));
#define KWAIT(N)                              \
  asm volatile("s_waitcnt vmcnt(" #N ")");    \
  __builtin_amdgcn_sched_barrier(0);
#define KMFMA(S0, S1, S2, S3, KT, KS)                                                     \
  s[KT][0] = __builtin_amdgcn_mfma_f32_16x16x32_bf16((KS) ? asbf(qr1) : asbf(qr0), asbf(S0), s[KT][0], 0, 0, 0); \
  s[KT][1] = __builtin_amdgcn_mfma_f32_16x16x32_bf16((KS) ? asbf(qr1) : asbf(qr0), asbf(S1), s[KT][1], 0, 0, 0); \
  s[KT][2] = __builtin_amdgcn_mfma_f32_16x16x32_bf16((KS) ? asbf(qr1) : asbf(qr0), asbf(S2), s[KT][2], 0, 0, 0); \
  s[KT][3] = __builtin_amdgcn_mfma_f32_16x16x32_bf16((KS) ? asbf(qr1) : asbf(qr0), asbf(S3), s[KT][3], 0, 0, 0);

  // 8 units (kt,ks), 2-slot ring, one unit in flight ahead.
  KISSUE(kA0, kA1, kA2, kA3, 0, 0);
  KISSUE(kB0, kB1, kB2, kB3, 0, 1); KWAIT(4); KMFMA(kA0, kA1, kA2, kA3, 0, 0);
  KISSUE(kA0, kA1, kA2, kA3, 1, 0); KWAIT(4); KMFMA(kB0, kB1, kB2, kB3, 0, 1);
  KISSUE(kB0, kB1, kB2, kB3, 1, 1); KWAIT(4); KMFMA(kA0, kA1, kA2, kA3, 1, 0);
  KISSUE(kA0, kA1, kA2, kA3, 2, 0); KWAIT(4); KMFMA(kB0, kB1, kB2, kB3, 1, 1);
  KISSUE(kB0, kB1, kB2, kB3, 2, 1); KWAIT(4); KMFMA(kA0, kA1, kA2, kA3, 2, 0);
  KISSUE(kA0, kA1, kA2, kA3, 3, 0); KWAIT(4); KMFMA(kB0, kB1, kB2, kB3, 2, 1);
  KISSUE(kB0, kB1, kB2, kB3, 3, 1); KWAIT(4); KMFMA(kA0, kA1, kA2, kA3, 3, 0);
                                    KWAIT(0); KMFMA(kB0, kB1, kB2, kB3, 3, 1);

  // ---- softmax stats (r10/r2 form)
  float m[4], sg[4];
#pragma unroll
  for (int r = 0; r < 4; ++r) {
    float mloc = -1e30f;
#pragma unroll
    for (int kt = 0; kt < 4; ++kt)
#pragma unroll
      for (int n = 0; n < 4; ++n) mloc = fmaxf(mloc, s[kt][n][r]);
    mloc *= 0.125f;
#pragma unroll
    for (int off = 1; off < 16; off <<= 1) mloc = fmaxf(mloc, __shfl_xor(mloc, off));
    float ssum = 0.f;
#pragma unroll
    for (int kt = 0; kt < 4; ++kt)
#pragma unroll
      for (int n = 0; n < 4; ++n) {
        float e = __expf(s[kt][n][r] * 0.125f - mloc);
        s[kt][n][r] = e;
        ssum += e;
      }
#pragma unroll
    for (int off = 1; off < 16; off <<= 1) ssum += __shfl_xor(ssum, off);
    m[r] = mloc; sg[r] = ssum;
  }

  if (l15 == 0) {
#pragma unroll
    for (int r = 0; r < 4; ++r) {
      mS[w][kg * 4 + r] = m[r];
      sgS[w][kg * 4 + r] = sg[r];
    }
  }
  __syncthreads();

  float scal[4];
#pragma unroll
  for (int r = 0; r < 4; ++r) {
    int row = kg * 4 + r;
    float M = -1e30f;
#pragma unroll
    for (int ww = 0; ww < 8; ++ww) M = fmaxf(M, mS[ww][row]);
    float Sg = 0.f;
#pragma unroll
    for (int ww = 0; ww < 8; ++ww) Sg += sgS[ww][row] * __expf(mS[ww][row] - M);
    scal[r] = __expf(m[r] - M) / Sg;
  }

  float* wb = wts + (size_t)b * SS * SS;
  f32x4 oacc[4];
#pragma unroll
  for (int nh = 0; nh < 4; ++nh) oacc[nh] = f32x4{0.f, 0.f, 0.f, 0.f};

  for (int kt = 0; kt < 4; ++kt) {
#pragma unroll
    for (int n = 0; n < 4; ++n)
#pragma unroll
      for (int r = 0; r < 4; ++r)
        pf[w][kg * 4 + r][n * 16 + l15] = s[kt][n][r] * scal[r];
    asm volatile("s_waitcnt lgkmcnt(0)" ::: "memory");

#pragma unroll
    for (int i = 0; i < 4; ++i) {
      int row = i * 4 + kg;
      f32x4 pv4 = *(const f32x4*)&pf[w][row][l15 * 4];
      *(f32x4*)(wb + (size_t)(q0 + row) * SS + kv0 + kt * 64 + l15 * 4) = pv4;
    }

#pragma unroll
    for (int ks = 0; ks < 2; ++ks) {
      f32x4 pa = *(const f32x4*)&pf[w][l15][ks * 32 + kg * 8];
      f32x4 pb = *(const f32x4*)&pf[w][l15][ks * 32 + kg * 8 + 4];
      union { unsigned short us[8]; bf16x8 v; } pu;
#pragma unroll
      for (int i = 0; i < 4; ++i) { pu.us[i] = f2bf(pa[i]); pu.us[4 + i] = f2bf(pb[i]); }
#pragma unroll
      for (int nh = 0; nh < 4; ++nh) {
        bf16x8 vf = *(const bf16x8*)(Vtb + (size_t)(nh * 16 + l15) * SS + kv0 + kt * 64 + ks * 32 + kg * 8);
        oacc[nh] = __builtin_amdgcn_mfma_f32_16x16x32_bf16(pu.v, vf, oacc[nh], 0, 0, 0);
      }
    }
  }

#pragma unroll
  for (int nh = 0; nh < 4; ++nh)
#pragma unroll
    for (int r = 0; r < 4; ++r)
      pf[w][kg * 4 + r][nh * 16 + l15] = oacc[nh][r];
  __syncthreads();

  int tid = threadIdx.x;
#pragma unroll
  for (int half = 0; half < 2; ++half) {
    int e = tid + half * 512;
    int row = e >> 6, col = e & 63;
    float ssum = 0.f;
#pragma unroll
    for (int ww = 0; ww < 8; ++ww) ssum += pf[ww][row][col];
    out[((size_t)b * SS + q0 + row) * SH + col] = ssum;
  }
}

extern "C" void kernel_launch(void* const* d_in, const int* in_sizes, int n_in,
                              void* d_out, int out_size, void* d_ws, size_t ws_size,
                              hipStream_t stream) {
  const float* x  = (const float*)d_in[0];
  const float* Wq = (const float*)d_in[1];
  const float* Wk = (const float*)d_in[2];
  const float* Wv = (const float*)d_in[3];

  unsigned short* Wt = (unsigned short*)d_ws;                 // 192*1024
  unsigned short* Q  = Wt + 192 * 1024;                       // 16384*64
  unsigned short* K  = Q + 16384 * 64;                        // 16384*64
  unsigned short* Vt = K + 16384 * 64;                        // 8*64*2048

  float* out = (float*)d_out;
  float* wts = out + (size_t)SB * SS * SH;

  prep_wt<<<768, 256, 0, stream>>>(Wq, Wk, Wv, Wt);
  proj<<<256, 512, 0, stream>>>(x, Wt, Q, K, Vt);
  attn<<<1024, 512, 0, stream>>>(Q, K, Vt, out, wts);
}

// Round 12
// 93.011 us; speedup vs baseline: 1.0872x; 1.0872x over previous
//
#include <hip/hip_runtime.h>

#define SB 8
#define SS 2048
#define SD 1024
#define SH 64

typedef float f32x4 __attribute__((ext_vector_type(4)));
typedef __bf16 bf16x8 __attribute__((ext_vector_type(8)));

__device__ __forceinline__ unsigned short f2bf(float f) {
  union { float f; unsigned int u; } v; v.f = f;
  unsigned int u = v.u;
  unsigned int r = u + 0x7FFFu + ((u >> 16) & 1u);
  return (unsigned short)(r >> 16);
}

// Wt[hc][d] = W_{hc/64}[d][hc&63] as bf16, hc in [0,192), d in [0,1024)
__global__ void prep_wt(const float* __restrict__ Wq, const float* __restrict__ Wk,
                        const float* __restrict__ Wv, unsigned short* __restrict__ Wt) {
  int idx = blockIdx.x * 256 + threadIdx.x;
  int hc = idx >> 10, d = idx & 1023;
  const float* W = (hc < 64) ? Wq : (hc < 128) ? Wk : Wv;
  int h = hc & 63;
  Wt[idx] = f2bf(W[d * SH + h]);
}

// QKV projection v4: M=16384, N=192, K=1024. 512 blocks x 512 thr = 2 blocks/CU
// (barrier-drain stalls of one block overlap the other block's compute).
// Block = 32 rows x 192 cols; wave = 16 rows x 48 cols (6 MFMA/step).
// B-tile (24 KB/step) DMA-staged dbuf via global_load_lds (pre-swizzled src);
// A-tile (4 KB) f32->bf16 dbuf; ONE barrier per K-step; x prefetched 2 ahead.
// LDS = 2x24 + 2x4 = 56 KB -> exactly 2 blocks/CU.
__global__ void __launch_bounds__(512, 2) proj(
    const float* __restrict__ x, const unsigned short* __restrict__ Wt,
    unsigned short* __restrict__ Q, unsigned short* __restrict__ K,
    unsigned short* __restrict__ Vt) {
  __shared__ unsigned short xs[2][32 * 64];     // 2 x 4 KB A tiles
  __shared__ unsigned short Bl[2][192 * 64];    // 2 x 24 KB B tiles

  int tid = threadIdx.x;
  int w = tid >> 6, lane = tid & 63;
  int l15 = lane & 15, kg = lane >> 4;
  int wr = w >> 2, wc = w & 3;
  int m0 = blockIdx.x * 32;

  // A staging: 16 thr/row, 4 f32 each -> one 8B LDS write after cvt
  int srow = tid >> 4, sseg = tid & 15;
  const float* xp = x + (size_t)(m0 + srow) * SD + sseg * 4;
  int swoff = srow * 64 + (((sseg >> 1) ^ (srow & 7)) << 3) + ((sseg & 1) << 2);

#define STAGEB(tt, buf)                                                          \
  {                                                                              \
    _Pragma("unroll") for (int j = 0; j < 3; ++j) {                              \
      int Lb = w * 1024 + j * 8192 + lane * 16;                                  \
      int c = Lb >> 7, cb = Lb & 127;                                            \
      const char* srcp = (const char*)Wt + (size_t)c * 2048 + (tt) * 128 +       \
                         (cb ^ ((c & 7) << 4));                                  \
      __builtin_amdgcn_global_load_lds(                                          \
          (const __attribute__((address_space(1))) unsigned int*)(const void*)srcp, \
          (__attribute__((address_space(3))) unsigned int*)(void*)                \
              ((char*)&Bl[(buf)][0] + w * 1024 + j * 8192),                      \
          16, 0, 0);                                                             \
    }                                                                            \
  }

#define CVTW(RA, buf)                                                           \
  {                                                                             \
    ushort4 cv;                                                                 \
    cv.x = f2bf((RA).x); cv.y = f2bf((RA).y);                                   \
    cv.z = f2bf((RA).z); cv.w = f2bf((RA).w);                                   \
    *(ushort4*)(&xs[(buf)][0] + swoff) = cv;                                    \
  }

  f32x4 acc[3];
#pragma unroll
  for (int nt = 0; nt < 3; ++nt) acc[nt] = f32x4{0.f, 0.f, 0.f, 0.f};

  float4 ra = *(const float4*)xp;            // x(0)
  STAGEB(0, 0);
  CVTW(ra, 0);
  ra = *(const float4*)(xp + 64);            // x(1)
  __syncthreads();                           // publishes A(0), drains B(0) DMA

  for (int t = 0; t < 16; ++t) {
    int cur = t & 1, nxt = (t + 1) & 1;
    if (t < 15) CVTW(ra, nxt);
    if (t < 14) ra = *(const float4*)(xp + (t + 2) * 64);
    if (t < 15) STAGEB(t + 1, nxt);

    const char* Bb = (const char*)&Bl[cur][0];
#pragma unroll
    for (int ks = 0; ks < 2; ++ks) {
      int row = wr * 16 + l15;
      int cg = ks * 4 + kg;
      bf16x8 af = *(const bf16x8*)(&xs[cur][0] + row * 64 + ((cg ^ (row & 7)) << 3));
#pragma unroll
      for (int nt = 0; nt < 3; ++nt) {
        int c = wc * 48 + nt * 16 + l15;
        int kb = (ks * 32 + kg * 8) * 2;
        bf16x8 bfr = *(const bf16x8*)(Bb + c * 128 + (kb ^ ((c & 7) << 4)));
        acc[nt] = __builtin_amdgcn_mfma_f32_16x16x32_bf16(af, bfr, acc[nt], 0, 0, 0);
      }
    }
    __syncthreads();  // publishes A(t+1), drains B(t+1) DMA + x(t+2)
  }

#pragma unroll
  for (int nt = 0; nt < 3; ++nt) {
    int c = wc * 48 + nt * 16 + l15;
    int mat = c >> 6, h = c & 63;
#pragma unroll
    for (int r = 0; r < 4; ++r) {
      int row = m0 + wr * 16 + kg * 4 + r;
      unsigned short bv = f2bf(acc[nt][r]);
      if (mat == 0) {
        Q[(size_t)row * SH + h] = bv;
      } else if (mat == 1) {
        K[(size_t)row * SH + h] = bv;
      } else {
        int bb = row >> 11, key = row & 2047;
        Vt[((size_t)bb * SH + h) * SS + key] = bv;
      }
    }
  }
}

// Attention (r2/r10 best-measured version, unchanged).
// Single pass, KV-split x8. 1024 blocks x 512 thr, 4 blocks/CU.
__global__ void __launch_bounds__(512, 4) attn(
    const unsigned short* __restrict__ Q, const unsigned short* __restrict__ Kb,
    const unsigned short* __restrict__ Vt, float* __restrict__ out,
    float* __restrict__ wts) {
  __shared__ float pf[8][16][68];
  __shared__ float mS[8][16], sgS[8][16];

  int b = blockIdx.x & 7, rg = blockIdx.x >> 3;
  int w = threadIdx.x >> 6, lane = threadIdx.x & 63;
  int l15 = lane & 15, kg = lane >> 4;
  int q0 = rg * 16;
  int kv0 = w * 256;

  const unsigned short* Qb  = Q  + (size_t)b * SS * SH;
  const unsigned short* Kbb = Kb + (size_t)b * SS * SH;
  const unsigned short* Vtb = Vt + (size_t)b * SH * SS;

  bf16x8 qf[2];
#pragma unroll
  for (int ks = 0; ks < 2; ++ks)
    qf[ks] = *(const bf16x8*)(Qb + (size_t)(q0 + l15) * SH + ks * 32 + kg * 8);

  f32x4 s[4][4];
#pragma unroll
  for (int kt = 0; kt < 4; ++kt)
#pragma unroll
    for (int n = 0; n < 4; ++n) s[kt][n] = f32x4{0.f, 0.f, 0.f, 0.f};

  for (int kt = 0; kt < 4; ++kt) {
#pragma unroll
    for (int ks = 0; ks < 2; ++ks)
#pragma unroll
      for (int n = 0; n < 4; ++n) {
        bf16x8 kf = *(const bf16x8*)(Kbb + (size_t)(kv0 + kt * 64 + n * 16 + l15) * SH + ks * 32 + kg * 8);
        s[kt][n] = __builtin_amdgcn_mfma_f32_16x16x32_bf16(qf[ks], kf, s[kt][n], 0, 0, 0);
      }
  }

  float m[4], sg[4];
#pragma unroll
  for (int r = 0; r < 4; ++r) {
    float mloc = -1e30f;
#pragma unroll
    for (int kt = 0; kt < 4; ++kt)
#pragma unroll
      for (int n = 0; n < 4; ++n) mloc = fmaxf(mloc, s[kt][n][r]);
    mloc *= 0.125f;
#pragma unroll
    for (int off = 1; off < 16; off <<= 1) mloc = fmaxf(mloc, __shfl_xor(mloc, off));
    float ssum = 0.f;
#pragma unroll
    for (int kt = 0; kt < 4; ++kt)
#pragma unroll
      for (int n = 0; n < 4; ++n) {
        float e = __expf(s[kt][n][r] * 0.125f - mloc);
        s[kt][n][r] = e;
        ssum += e;
      }
#pragma unroll
    for (int off = 1; off < 16; off <<= 1) ssum += __shfl_xor(ssum, off);
    m[r] = mloc; sg[r] = ssum;
  }

  if (l15 == 0) {
#pragma unroll
    for (int r = 0; r < 4; ++r) {
      mS[w][kg * 4 + r] = m[r];
      sgS[w][kg * 4 + r] = sg[r];
    }
  }
  __syncthreads();

  float scal[4];
#pragma unroll
  for (int r = 0; r < 4; ++r) {
    int row = kg * 4 + r;
    float M = -1e30f;
#pragma unroll
    for (int ww = 0; ww < 8; ++ww) M = fmaxf(M, mS[ww][row]);
    float Sg = 0.f;
#pragma unroll
    for (int ww = 0; ww < 8; ++ww) Sg += sgS[ww][row] * __expf(mS[ww][row] - M);
    scal[r] = __expf(m[r] - M) / Sg;
  }

  float* wb = wts + (size_t)b * SS * SS;
  f32x4 oacc[4];
#pragma unroll
  for (int nh = 0; nh < 4; ++nh) oacc[nh] = f32x4{0.f, 0.f, 0.f, 0.f};

  for (int kt = 0; kt < 4; ++kt) {
#pragma unroll
    for (int n = 0; n < 4; ++n)
#pragma unroll
      for (int r = 0; r < 4; ++r)
        pf[w][kg * 4 + r][n * 16 + l15] = s[kt][n][r] * scal[r];
    asm volatile("s_waitcnt lgkmcnt(0)" ::: "memory");

#pragma unroll
    for (int i = 0; i < 4; ++i) {
      int row = i * 4 + kg;
      f32x4 pv4 = *(const f32x4*)&pf[w][row][l15 * 4];
      *(f32x4*)(wb + (size_t)(q0 + row) * SS + kv0 + kt * 64 + l15 * 4) = pv4;
    }

#pragma unroll
    for (int ks = 0; ks < 2; ++ks) {
      f32x4 pa = *(const f32x4*)&pf[w][l15][ks * 32 + kg * 8];
      f32x4 pb = *(const f32x4*)&pf[w][l15][ks * 32 + kg * 8 + 4];
      union { unsigned short us[8]; bf16x8 v; } pu;
#pragma unroll
      for (int i = 0; i < 4; ++i) { pu.us[i] = f2bf(pa[i]); pu.us[4 + i] = f2bf(pb[i]); }
#pragma unroll
      for (int nh = 0; nh < 4; ++nh) {
        bf16x8 vf = *(const bf16x8*)(Vtb + (size_t)(nh * 16 + l15) * SS + kv0 + kt * 64 + ks * 32 + kg * 8);
        oacc[nh] = __builtin_amdgcn_mfma_f32_16x16x32_bf16(pu.v, vf, oacc[nh], 0, 0, 0);
      }
    }
  }

#pragma unroll
  for (int nh = 0; nh < 4; ++nh)
#pragma unroll
    for (int r = 0; r < 4; ++r)
      pf[w][kg * 4 + r][nh * 16 + l15] = oacc[nh][r];
  __syncthreads();

  int tid = threadIdx.x;
#pragma unroll
  for (int half = 0; half < 2; ++half) {
    int e = tid + half * 512;
    int row = e >> 6, col = e & 63;
    float ssum = 0.f;
#pragma unroll
    for (int ww = 0; ww < 8; ++ww) ssum += pf[ww][row][col];
    out[((size_t)b * SS + q0 + row) * SH + col] = ssum;
  }
}

extern "C" void kernel_launch(void* const* d_in, const int* in_sizes, int n_in,
                              void* d_out, int out_size, void* d_ws, size_t ws_size,
                              hipStream_t stream) {
  const float* x  = (const float*)d_in[0];
  const float* Wq = (const float*)d_in[1];
  const float* Wk = (const float*)d_in[2];
  const float* Wv = (const float*)d_in[3];

  unsigned short* Wt = (unsigned short*)d_ws;                 // 192*1024
  unsigned short* Q  = Wt + 192 * 1024;                       // 16384*64
  unsigned short* K  = Q + 16384 * 64;                        // 16384*64
  unsigned short* Vt = K + 16384 * 64;                        // 8*64*2048

  float* out = (float*)d_out;
  float* wts = out + (size_t)SB * SS * SH;

  prep_wt<<<768, 256, 0, stream>>>(Wq, Wk, Wv, Wt);
  proj<<<512, 512, 0, stream>>>(x, Wt, Q, K, Vt);
  attn<<<1024, 512, 0, stream>>>(Q, K, Vt, out, wts);
}